// Round 1
// baseline (105.582 us; speedup 1.0000x reference)
//
#include <hip/hip_runtime.h>

// Problem: B=4, L=2048, H=8, D=64.
// Reference math collapses to: out[m,q,h,d] = sum_e values[m,e,h,d]
// (softmax row-sum over w is exactly 1; einsum sums w and e independently).
// So: reduce values over the sequence axis, broadcast over q.

#define Bm     4
#define Lseq   2048
#define HD     512          // H*D
#define C4     128          // HD / 4  (float4 columns per row)
#define NCHUNK 128          // e-chunks per batch
#define CH_E   (Lseq / NCHUNK)   // 16 rows per chunk

// ---------------------------------------------------------------------------
// Kernel 1: partial-reduce values over e, atomicAdd into vsum[Bm*HD] (in ws).
// grid = Bm*NCHUNK blocks, 256 threads.
// Thread t: column c4 = t&127, sub-half sub = t>>7 handles 8 consecutive rows.
// Reads are perfectly coalesced: a wave reads 64 consecutive float4s per row.
// ---------------------------------------------------------------------------
__global__ void vsum_reduce(const float4* __restrict__ v4,
                            float* __restrict__ vsum) {
    const int m   = blockIdx.x / NCHUNK;
    const int ch  = blockIdx.x % NCHUNK;
    const int t   = threadIdx.x;
    const int c4  = t & (C4 - 1);
    const int sub = t >> 7;  // 0 or 1

    const float4* base =
        v4 + (size_t)(m * Lseq + ch * CH_E + sub * (CH_E / 2)) * C4 + c4;

    float4 acc = make_float4(0.f, 0.f, 0.f, 0.f);
#pragma unroll
    for (int i = 0; i < CH_E / 2; ++i) {
        float4 x = base[(size_t)i * C4];
        acc.x += x.x; acc.y += x.y; acc.z += x.z; acc.w += x.w;
    }

    __shared__ float4 red[C4];
    if (sub) red[c4] = acc;
    __syncthreads();
    if (!sub) {
        float4 o = red[c4];
        acc.x += o.x; acc.y += o.y; acc.z += o.z; acc.w += o.w;
        float* dst = vsum + m * HD + c4 * 4;
        atomicAdd(dst + 0, acc.x);
        atomicAdd(dst + 1, acc.y);
        atomicAdd(dst + 2, acc.z);
        atomicAdd(dst + 3, acc.w);
    }
}

// ---------------------------------------------------------------------------
// Kernel 2: broadcast vsum across the q dimension.
// out[m,q,h,d] = vsum[m,h,d].  One float4 store per thread, coalesced.
// grid = Bm*Lseq*C4 / 256 = 4096 blocks.
// ---------------------------------------------------------------------------
__global__ void vsum_broadcast(const float4* __restrict__ vsum4,
                               float4* __restrict__ out4) {
    const int idx = blockIdx.x * blockDim.x + threadIdx.x;  // 0 .. Bm*Lseq*C4
    const int c4  = idx & (C4 - 1);
    const int m   = idx >> 18;  // Lseq*C4 = 2^18
    out4[idx] = vsum4[m * C4 + c4];
}

extern "C" void kernel_launch(void* const* d_in, const int* in_sizes, int n_in,
                              void* d_out, int out_size, void* d_ws, size_t ws_size,
                              hipStream_t stream) {
    // inputs: d_in[0]=queries (unused), d_in[1]=keys (unused), d_in[2]=values
    const float* values = (const float*)d_in[2];
    float*       out    = (float*)d_out;
    float*       vsum   = (float*)d_ws;   // Bm*HD floats = 8 KB scratch

    hipMemsetAsync(d_ws, 0, Bm * HD * sizeof(float), stream);

    vsum_reduce<<<Bm * NCHUNK, 256, 0, stream>>>((const float4*)values, vsum);

    const int total4 = Bm * Lseq * C4;           // 1,048,576 float4 stores
    vsum_broadcast<<<total4 / 256, 256, 0, stream>>>((const float4*)vsum,
                                                     (float4*)out);
}

// Round 2
// 96.062 us; speedup vs baseline: 1.0991x; 1.0991x over previous
//
#include <hip/hip_runtime.h>

// Problem: B=4, L=2048, H=8, D=64.
// Reference math collapses to: out[m,q,h,d] = sum_e values[m,e,h,d]
// (softmax row-sum over w is exactly 1; the einsum sums w and e independently).
// Structure: k1 partial column-sums (no atomics, no init), k2 fold partials,
// k3 broadcast. Q and K are never read.

#define Bm     4
#define Lseq   2048
#define HD     512                 // H*D
#define C4     128                 // HD / 4 (float4 columns per row)
#define NCHUNK 128                 // e-chunks per batch
#define CH_E   (Lseq / NCHUNK)     // 16 rows per chunk
#define PART_FLOATS (Bm * NCHUNK * HD)   // 262144 floats = 1 MB of partials
// ws layout: [0, 1MB) = partials, [1MB, 1MB+8KB) = vsum

// ---------------------------------------------------------------------------
// k1: each block reduces 16 consecutive e-rows of one batch to a 512-float
// partial row; plain float4 stores (no init, no atomics).
// grid = Bm*NCHUNK = 512 blocks, 256 threads.
// ---------------------------------------------------------------------------
__global__ void vsum_partial(const float4* __restrict__ v4,
                             float4* __restrict__ part4) {
    const int m   = blockIdx.x / NCHUNK;
    const int ch  = blockIdx.x % NCHUNK;
    const int t   = threadIdx.x;
    const int c4  = t & (C4 - 1);
    const int sub = t >> 7;  // 0 or 1: which 8-row half

    const float4* base =
        v4 + (size_t)(m * Lseq + ch * CH_E + sub * (CH_E / 2)) * C4 + c4;

    float4 acc = make_float4(0.f, 0.f, 0.f, 0.f);
#pragma unroll
    for (int i = 0; i < CH_E / 2; ++i) {
        float4 x = base[(size_t)i * C4];
        acc.x += x.x; acc.y += x.y; acc.z += x.z; acc.w += x.w;
    }

    __shared__ float4 red[C4];
    if (sub) red[c4] = acc;
    __syncthreads();
    if (!sub) {
        float4 o = red[c4];
        acc.x += o.x; acc.y += o.y; acc.z += o.z; acc.w += o.w;
        part4[(size_t)blockIdx.x * C4 + c4] = acc;
    }
}

// ---------------------------------------------------------------------------
// k2: fold 128 partial rows per (m, col) into vsum[Bm*HD].
// grid = 8 blocks x 256 threads = 2048 threads, one per output column.
// Consecutive threads read consecutive columns -> coalesced; data is L2-hot.
// ---------------------------------------------------------------------------
__global__ void vsum_final(const float* __restrict__ part,
                           float* __restrict__ vsum) {
    const int j   = blockIdx.x * blockDim.x + threadIdx.x;  // 0..2047
    const int m   = j >> 9;        // / HD
    const int col = j & (HD - 1);
    const float* p = part + (size_t)m * NCHUNK * HD + col;
    float s = 0.f;
#pragma unroll 8
    for (int ch = 0; ch < NCHUNK; ++ch) s += p[(size_t)ch * HD];
    vsum[j] = s;
}

// ---------------------------------------------------------------------------
// k3: broadcast vsum across the q dimension. One float4 store per thread.
// grid = Bm*Lseq*C4 / 256 = 4096 blocks.
// ---------------------------------------------------------------------------
__global__ void vsum_broadcast(const float4* __restrict__ vsum4,
                               float4* __restrict__ out4) {
    const int idx = blockIdx.x * blockDim.x + threadIdx.x;
    const int c4  = idx & (C4 - 1);
    const int m   = idx >> 18;  // Lseq*C4 = 2^18
    out4[idx] = vsum4[m * C4 + c4];
}

extern "C" void kernel_launch(void* const* d_in, const int* in_sizes, int n_in,
                              void* d_out, int out_size, void* d_ws, size_t ws_size,
                              hipStream_t stream) {
    // inputs: d_in[0]=queries (unused), d_in[1]=keys (unused), d_in[2]=values
    const float* values = (const float*)d_in[2];
    float*       part   = (float*)d_ws;                       // 1 MB partials
    float*       vsum   = (float*)d_ws + PART_FLOATS;         // 8 KB sums
    float*       out    = (float*)d_out;

    vsum_partial<<<Bm * NCHUNK, 256, 0, stream>>>((const float4*)values,
                                                  (float4*)part);

    vsum_final<<<(Bm * HD) / 256, 256, 0, stream>>>(part, vsum);

    const int total4 = Bm * Lseq * C4;  // 1,048,576 float4 stores
    vsum_broadcast<<<total4 / 256, 256, 0, stream>>>((const float4*)vsum,
                                                     (float4*)out);
}